// Round 2
// baseline (1457.811 us; speedup 1.0000x reference)
//
#include <hip/hip_runtime.h>
#include <math.h>

#define BB 32
#define LL 40
#define DD 128
#define NSB 64              // 2 seq * 32 batch
#define NU  (NSB * LL)      // 2560 (sb, t) pairs

typedef unsigned short u16;

__device__ __forceinline__ u16 f2bf(float f) {
    union { float f; unsigned u; } v; v.f = f;
    unsigned u = v.u;
    u += 0x7fff + ((u >> 16) & 1);   // RNE
    return (u16)(u >> 16);
}
__device__ __forceinline__ float bf2f(u16 b) {
    union { unsigned u; float f; } v; v.u = ((unsigned)b) << 16;
    return v.f;
}

__device__ __forceinline__ float sigm(float x) {
    return 1.f / (1.f + __expf(-x));
}
__device__ __forceinline__ float tanh_fast(float x) {
    x = fminf(fmaxf(x, -15.f), 15.f);
    float e = __expf(2.f * x);
    return (e - 1.f) / (e + 1.f);
}

// Gather xe rows (embed lookups) and inverse squared norms for all (sb, t).
__global__ void prep_kernel(const int* __restrict__ q, const int* __restrict__ a,
                            const float* __restrict__ embed,
                            float* __restrict__ xe_all, float* __restrict__ inv_all) {
    int u = blockIdx.x * 4 + (threadIdx.x >> 6);
    int lane = threadIdx.x & 63;
    if (u >= NU) return;
    int sb = u / LL, t = u % LL;
    int s = sb >> 5, b = sb & 31;
    const int* idx = s ? a : q;
    int e = idx[b * LL + t];
    const float* row = embed + (size_t)e * DD;
    float v0 = row[lane], v1 = row[lane + 64];
    xe_all[(size_t)u * DD + lane] = v0;
    xe_all[(size_t)u * DD + lane + 64] = v1;
    float d = v0 * v0 + v1 * v1;
    #pragma unroll
    for (int o = 32; o; o >>= 1) d += __shfl_down(d, o);
    if (lane == 0) inv_all[u] = 1.f / (d + 1e-4f);
}

// One "level sweep": computes output rows [row0_lev, row0_lev+nrows_lev) of one
// layer for ALL timesteps. Each thread owns one (row, col) pixel of one (sb)
// and scans t, keeping c in a register. Depends only on rows of strictly
// earlier levels at t-1 (already materialized in h), except the tail level
// (rows 126..127) whose self-reads are same-block prior-iteration global
// writes (ordered by __syncthreads).
// h layout: [t][sb][row][col] bf16.
__global__ __launch_bounds__(1024)
void level_kernel(const float* __restrict__ xe_all, const float* __restrict__ inv_all,
                  const float* __restrict__ conv_w, const float* __restrict__ conv_b,
                  const u16* __restrict__ xt_h,   // null => density input (layer1); else h1 (layer2)
                  u16* __restrict__ h,            // this layer's h buffer
                  float* __restrict__ pool,       // non-null for layer2: max over t
                  int layer, int row0_lev, int nrows_lev) {
    const int chunk = blockIdx.x;
    const int sb = blockIdx.y;
    const int row0 = row0_lev + chunk * 8;
    const int nr = min(8, row0_lev + nrows_lev - row0);   // rows this block owns

    const int tx = threadIdx.x;            // 0..127 (col)
    const int ty = threadIdx.y;            // 0..blockDim.y-1 (row within chunk)
    const int tid = ty * 128 + tx;
    const int nthr = blockDim.y * 128;

    __shared__ float ws_in[18][132];       // staged input window rows (col pad +-1)
    __shared__ float wls[48], bls[4];
    if (tid < 48) wls[tid] = conv_w[layer * 48 + tid];
    if (tid < 4)  bls[tid] = conv_b[layer * 4 + tid];

    const int rfirst = 2 * row0 - 1;       // first concat-input row needed
    const int rcount = 2 * nr + 2;         // rows needed
    const int i = row0 + ty;               // output row
    const bool active = ty < nr;

    const size_t planes = (size_t)DD * DD;
    float c_reg = 0.f, pool_reg = -1e30f;

    for (int t = 0; t < LL; ++t) {
        const int u = sb * LL + t;
        const float invv = xt_h ? 0.f : inv_all[u];
        const float* xe = xe_all + (size_t)u * DD;
        __syncthreads();                   // ws_in from previous t fully consumed

        for (int e = tid; e < rcount * 130; e += nthr) {
            int rr = e / 130, cc = e % 130 - 1;
            int r = rfirst + rr;
            float v = 0.f;
            if (cc >= 0 && cc < DD && r >= 0 && r < 2 * DD) {
                if (r < DD) {              // xt region of the concat
                    v = xt_h ? bf2f(xt_h[((size_t)t * NSB + sb) * planes + (size_t)r * DD + cc])
                             : xe[r] * xe[cc] * invv;
                } else if (t > 0) {        // recurrent h region
                    v = bf2f(h[((size_t)(t - 1) * NSB + sb) * planes + (size_t)(r - DD) * DD + cc]);
                }
            }
            ws_in[rr][cc + 1] = v;
        }
        __syncthreads();

        if (active) {
            float acc0 = bls[0], acc1 = bls[1], acc2 = bls[2], acc3 = bls[3];
            #pragma unroll
            for (int kh = 0; kh < 4; ++kh) {
                #pragma unroll
                for (int kw = 0; kw < 3; ++kw) {
                    float v = ws_in[2 * ty + kh][tx + kw];
                    acc0 += v * wls[0 * 12 + kh * 3 + kw];
                    acc1 += v * wls[1 * 12 + kh * 3 + kw];
                    acc2 += v * wls[2 * 12 + kh * 3 + kw];
                    acc3 += v * wls[3 * 12 + kh * 3 + kw];
                }
            }
            float fg = sigm(acc0);
            float ig = sigm(acc1);
            float og = sigm(acc2);
            float cs = tanh_fast(acc3);
            c_reg = fg * c_reg + ig * cs;
            float hn = og * tanh_fast(c_reg);
            h[((size_t)t * NSB + sb) * planes + (size_t)i * DD + tx] = f2bf(hn);
            pool_reg = fmaxf(pool_reg, hn);
        }
    }

    if (pool && active)
        pool[(size_t)sb * planes + (size_t)i * DD + tx] = pool_reg;
}

// score = qa @ lin_w.T + lin_b; out = log_softmax(score)
__global__ void final_kernel(const float* __restrict__ pool,   // [sb][D*D] f32
                             const float* __restrict__ lin_w,  // [2][2*D*D]
                             const float* __restrict__ lin_b,  // [2]
                             float* __restrict__ out) {
    const int b = blockIdx.x;
    const int tid = threadIdx.x;  // 256
    const int DD2 = DD * DD;
    const float* pq = pool + (size_t)b * DD2;
    const float* pa = pool + (size_t)(BB + b) * DD2;
    float s0 = 0.f, s1 = 0.f;
    for (int j = tid; j < DD2; j += 256) {
        float vq = pq[j], va = pa[j];
        s0 += vq * lin_w[j]           + va * lin_w[DD2 + j];
        s1 += vq * lin_w[2 * DD2 + j] + va * lin_w[3 * DD2 + j];
    }
    #pragma unroll
    for (int o = 32; o; o >>= 1) {
        s0 += __shfl_down(s0, o);
        s1 += __shfl_down(s1, o);
    }
    __shared__ float sh0[4], sh1[4];
    int wid = tid >> 6, lane = tid & 63;
    if (lane == 0) { sh0[wid] = s0; sh1[wid] = s1; }
    __syncthreads();
    if (tid == 0) {
        float a0 = sh0[0] + sh0[1] + sh0[2] + sh0[3] + lin_b[0];
        float a1 = sh1[0] + sh1[1] + sh1[2] + sh1[3] + lin_b[1];
        float m = fmaxf(a0, a1);
        float lse = m + logf(expf(a0 - m) + expf(a1 - m));
        out[b * 2 + 0] = a0 - lse;
        out[b * 2 + 1] = a1 - lse;
    }
}

extern "C" void kernel_launch(void* const* d_in, const int* in_sizes, int n_in,
                              void* d_out, int out_size, void* d_ws, size_t ws_size,
                              hipStream_t stream) {
    const int*   q      = (const int*)d_in[0];
    const int*   a      = (const int*)d_in[1];
    const float* embed  = (const float*)d_in[2];
    const float* conv_w = (const float*)d_in[3];
    const float* conv_b = (const float*)d_in[4];
    const float* lin_w  = (const float*)d_in[5];
    const float* lin_b  = (const float*)d_in[6];
    float* out = (float*)d_out;

    // Workspace: xe_all (NU*128 f32) | inv_all (NU f32) | pool (64*16384 f32)
    //            | h1 (40*64*16384 bf16 = 84MB) | h2 (84MB). Total ~178MB.
    const size_t planes = (size_t)DD * DD;
    float* ws      = (float*)d_ws;
    float* xe_all  = ws;
    float* inv_all = xe_all + (size_t)NU * DD;
    float* pool    = inv_all + NU;
    u16*   h1      = (u16*)(pool + (size_t)NSB * planes);
    u16*   h2      = h1 + (size_t)LL * NSB * planes;

    prep_kernel<<<(NU + 3) / 4, 256, 0, stream>>>(q, a, embed, xe_all, inv_all);

    // Level schedule: level(i) = 1 + level(2i-126); rows 0..62 depth 0; tail 126..127.
    const int levs[8][2] = {{0,63},{63,32},{95,16},{111,8},{119,4},{123,2},{125,1},{126,2}};
    for (int layer = 0; layer < 2; ++layer) {
        const u16* xt = layer ? h1 : nullptr;
        u16* hh       = layer ? h2 : h1;
        float* pl     = layer ? pool : nullptr;
        for (int k = 0; k < 8; ++k) {
            int r0 = levs[k][0], nrl = levs[k][1];
            int nchunks = (nrl + 7) / 8;
            dim3 blk(128, nrl < 8 ? nrl : 8);
            dim3 grd(nchunks, NSB);
            level_kernel<<<grd, blk, 0, stream>>>(xe_all, inv_all, conv_w, conv_b,
                                                  xt, hh, pl, layer, r0, nrl);
        }
    }

    final_kernel<<<BB, 256, 0, stream>>>(pool, lin_w, lin_b, out);
}

// Round 3
// 834.267 us; speedup vs baseline: 1.7474x; 1.7474x over previous
//
#include <hip/hip_runtime.h>
#include <math.h>

#define BB 32
#define LL 40
#define DD 128
#define NSB 64              // 2 seq * 32 batch
#define NU  (NSB * LL)      // 2560 (sb, t) pairs

typedef unsigned short u16;

__device__ __forceinline__ u16 f2bf(float f) {
    union { float f; unsigned u; } v; v.f = f;
    unsigned u = v.u;
    u += 0x7fff + ((u >> 16) & 1);   // RNE
    return (u16)(u >> 16);
}
__device__ __forceinline__ float bf2f(u16 b) {
    union { unsigned u; float f; } v; v.u = ((unsigned)b) << 16;
    return v.f;
}
__device__ __forceinline__ float sigm(float x) {
    return 1.f / (1.f + __expf(-x));
}
__device__ __forceinline__ float tanh_fast(float x) {
    x = fminf(fmaxf(x, -15.f), 15.f);
    float e = __expf(2.f * x);
    return (e - 1.f) / (e + 1.f);
}

// ---------------- prep: xe rows + inverse squared norms ----------------
__global__ void prep_kernel(const int* __restrict__ q, const int* __restrict__ a,
                            const float* __restrict__ embed,
                            float* __restrict__ xe_all, float* __restrict__ inv_all) {
    int u = blockIdx.x * 4 + (threadIdx.x >> 6);
    int lane = threadIdx.x & 63;
    if (u >= NU) return;
    int sb = u / LL, t = u % LL;
    int s = sb >> 5, b = sb & 31;
    const int* idx = s ? a : q;
    int e = idx[b * LL + t];
    const float* row = embed + (size_t)e * DD;
    float v0 = row[lane], v1 = row[lane + 64];
    xe_all[(size_t)u * DD + lane] = v0;
    xe_all[(size_t)u * DD + lane + 64] = v1;
    float d = v0 * v0 + v1 * v1;
    #pragma unroll
    for (int o = 32; o; o >>= 1) d += __shfl_down(d, o);
    if (lane == 0) inv_all[u] = 1.f / (d + 1e-4f);
}

// ---------------- layer1 level0 (rows 0..62): separable density conv ----------------
// density = inv * xe (x) xe  (rank-1)  =>  conv factorizes: 12 FMA/px instead of 48.
// Thread owns pixel (i, c); serial t with c in register. Grid (32, 64), block (128,2).
__global__ __launch_bounds__(256)
void lev0_l1_kernel(const float* __restrict__ xe_all, const float* __restrict__ inv_all,
                    const float* __restrict__ conv_w, const float* __restrict__ conv_b,
                    u16* __restrict__ h1) {
    const int chunk = blockIdx.x, sb = blockIdx.y;
    const int r0 = 2 * chunk;
    const int tx = threadIdx.x, ty = threadIdx.y;
    const int tid = ty * 128 + tx;
    __shared__ float xe_s[DD];
    __shared__ float us[2][12];
    __shared__ float wls[48], bls[4];
    if (tid < 48) wls[tid] = conv_w[tid];
    if (tid < 4)  bls[tid] = conv_b[tid];
    const int i = r0 + ty;
    const bool act = (i < 63);
    const size_t plane = (size_t)DD * DD;
    float c_reg = 0.f;
    for (int t = 0; t < LL; ++t) {
        const int u = sb * LL + t;
        __syncthreads();
        if (tid < DD) xe_s[tid] = xe_all[(size_t)u * DD + tid];
        __syncthreads();
        if (tid < 24) {
            int iy = tid / 12, rem = tid % 12, g = rem / 3, kw = rem % 3;
            int base = 2 * (r0 + iy) - 1;
            float s = 0.f;
            #pragma unroll
            for (int kh = 0; kh < 4; ++kh) {
                int rr = base + kh;
                float v = (rr >= 0 && rr < DD) ? xe_s[rr] : 0.f;
                s += wls[g * 12 + kh * 3 + kw] * v;
            }
            us[iy][g * 3 + kw] = s;
        }
        __syncthreads();
        float invv = inv_all[u];
        float xl = tx > 0 ? xe_s[tx - 1] : 0.f;
        float xm = xe_s[tx];
        float xr = tx < 127 ? xe_s[tx + 1] : 0.f;
        float acc[4];
        #pragma unroll
        for (int g = 0; g < 4; ++g)
            acc[g] = bls[g] + invv * (us[ty][g * 3 + 0] * xl + us[ty][g * 3 + 1] * xm
                                      + us[ty][g * 3 + 2] * xr);
        float fg = sigm(acc[0]), ig = sigm(acc[1]), og = sigm(acc[2]), cs = tanh_fast(acc[3]);
        c_reg = fg * c_reg + ig * cs;
        float hn = og * tanh_fast(c_reg);
        if (act) h1[((size_t)t * NSB + sb) * plane + (size_t)i * DD + tx] = f2bf(hn);
    }
}

// ---------------- layer2 level0 (rows 0..62): direct conv from h1 ----------------
__global__ __launch_bounds__(256)
void lev0_l2_kernel(const u16* __restrict__ h1,
                    const float* __restrict__ conv_w, const float* __restrict__ conv_b,
                    u16* __restrict__ h2, float* __restrict__ pool) {
    const int chunk = blockIdx.x, sb = blockIdx.y;
    const int tx = threadIdx.x, ty = threadIdx.y;
    const int tid = ty * 128 + tx;
    __shared__ float win[6][130];
    __shared__ float wls[48], bls[4];
    if (tid < 48) wls[tid] = conv_w[48 + tid];
    if (tid < 4)  bls[tid] = conv_b[4 + tid];
    const int i = 2 * chunk + ty;
    const bool act = (i < 63);
    const size_t plane = (size_t)DD * DD;
    float c_reg = 0.f, pr = -1e30f;
    for (int t = 0; t < LL; ++t) {
        const u16* xt = h1 + ((size_t)t * NSB + sb) * plane;
        __syncthreads();
        for (int e = tid; e < 6 * 130; e += 256) {
            int rr = e / 130, cc = e % 130 - 1;
            int cr = 4 * chunk - 1 + rr;
            float v = 0.f;
            if (cc >= 0 && cc < DD && cr >= 0 && cr < DD)
                v = bf2f(xt[(size_t)cr * DD + cc]);
            win[rr][cc + 1] = v;
        }
        __syncthreads();
        float a0 = bls[0], a1 = bls[1], a2 = bls[2], a3 = bls[3];
        #pragma unroll
        for (int kh = 0; kh < 4; ++kh) {
            #pragma unroll
            for (int kw = 0; kw < 3; ++kw) {
                float v = win[2 * ty + kh][tx + kw];
                a0 += v * wls[0 * 12 + kh * 3 + kw];
                a1 += v * wls[1 * 12 + kh * 3 + kw];
                a2 += v * wls[2 * 12 + kh * 3 + kw];
                a3 += v * wls[3 * 12 + kh * 3 + kw];
            }
        }
        float fg = sigm(a0), ig = sigm(a1), og = sigm(a2), cs = tanh_fast(a3);
        c_reg = fg * c_reg + ig * cs;
        float hn = og * tanh_fast(c_reg);
        if (act) {
            h2[((size_t)t * NSB + sb) * plane + (size_t)i * DD + tx] = f2bf(hn);
            pr = fmaxf(pr, hn);
        }
    }
    if (act) pool[(size_t)sb * plane + (size_t)i * DD + tx] = pr;
}

// ---------------- gates for one level: parallel over (pixel, t) ----------------
// grid (nrows/R, NSB, LL), block (128, R). Writes fg, ig*cs, og (f32 scratch).
__global__ __launch_bounds__(1024)
void gates_kernel(const float* __restrict__ xe_all, const float* __restrict__ inv_all,
                  const float* __restrict__ conv_w, const float* __restrict__ conv_b,
                  const u16* __restrict__ xt_h,   // null => layer1 density; else h1
                  const u16* __restrict__ h_own,  // own layer h (read at t-1)
                  float* __restrict__ g_fg, float* __restrict__ g_ic, float* __restrict__ g_og,
                  int layer, int row0_lev, int nrows_lev, int R) {
    const int chunk = blockIdx.x, sb = blockIdx.y, t = blockIdx.z;
    const int row0 = row0_lev + chunk * R;
    const int tx = threadIdx.x, ty = threadIdx.y;
    const int tid = ty * 128 + tx, nthr = R * 128;
    __shared__ float win[18][130];
    __shared__ float xe_s[DD];
    __shared__ float wls[48], bls[4];
    if (tid < 48) wls[tid] = conv_w[layer * 48 + tid];
    if (tid < 4)  bls[tid] = conv_b[layer * 4 + tid];
    const size_t plane = (size_t)DD * DD;
    const int rfirst = 2 * row0 - 1;
    const int rcount = 2 * R + 2;
    float invv = 0.f;
    const bool need_xe = (layer == 0) && (rfirst < DD);
    if (need_xe) {
        if (tid < DD) xe_s[tid] = xe_all[((size_t)sb * LL + t) * DD + tid];
        invv = inv_all[sb * LL + t];
    }
    __syncthreads();
    for (int e = tid; e < rcount * 130; e += nthr) {
        int rr = e / 130, cc = e % 130 - 1;
        int cr = rfirst + rr;
        float v = 0.f;
        if (cc >= 0 && cc < DD && cr >= 0 && cr < 2 * DD) {
            if (cr < DD)
                v = (layer == 0) ? xe_s[cr] * xe_s[cc] * invv
                                 : bf2f(xt_h[((size_t)t * NSB + sb) * plane + (size_t)cr * DD + cc]);
            else if (t > 0)
                v = bf2f(h_own[((size_t)(t - 1) * NSB + sb) * plane + (size_t)(cr - DD) * DD + cc]);
        }
        win[rr][cc + 1] = v;
    }
    __syncthreads();
    float a0 = bls[0], a1 = bls[1], a2 = bls[2], a3 = bls[3];
    #pragma unroll
    for (int kh = 0; kh < 4; ++kh) {
        #pragma unroll
        for (int kw = 0; kw < 3; ++kw) {
            float v = win[2 * ty + kh][tx + kw];
            a0 += v * wls[0 * 12 + kh * 3 + kw];
            a1 += v * wls[1 * 12 + kh * 3 + kw];
            a2 += v * wls[2 * 12 + kh * 3 + kw];
            a3 += v * wls[3 * 12 + kh * 3 + kw];
        }
    }
    size_t gi = (((size_t)t * NSB + sb) * nrows_lev + (chunk * R + ty)) * DD + tx;
    g_fg[gi] = sigm(a0);
    g_ic[gi] = sigm(a1) * tanh_fast(a3);
    g_og[gi] = sigm(a2);
}

// ---------------- scan: c-recurrence over t, thread per pixel ----------------
__global__ __launch_bounds__(256)
void scan_kernel(const float* __restrict__ g_fg, const float* __restrict__ g_ic,
                 const float* __restrict__ g_og,
                 u16* __restrict__ h_own, float* __restrict__ pool,
                 int row0_lev, int nrows_lev, int log2nr) {
    const int id = blockIdx.x * 256 + threadIdx.x;
    const int c = id & 127;
    const int r = (id >> 7) & (nrows_lev - 1);
    const int sb = id >> (7 + log2nr);
    const size_t plane = (size_t)DD * DD;
    const size_t step = (size_t)NSB * nrows_lev * DD;
    size_t gi = ((size_t)sb * nrows_lev + r) * DD + c;
    const size_t hi = (size_t)sb * plane + (size_t)(row0_lev + r) * DD + c;
    float cc = 0.f, pr = -1e30f;
    for (int t = 0; t < LL; ++t) {
        float fg = g_fg[gi], ic = g_ic[gi], og = g_og[gi];
        cc = fg * cc + ic;
        float hn = og * tanh_fast(cc);
        h_own[(size_t)t * NSB * plane + hi] = f2bf(hn);
        pr = fmaxf(pr, hn);
        gi += step;
    }
    if (pool) pool[hi] = pr;
}

// ---------------- serial tail: rows 123..127 (self-recurrent cluster) ----------------
// One block per sb; own rows LDS ping-pong; rows 117..122 read from global (earlier levels).
__global__ __launch_bounds__(640)
void tail_kernel(const float* __restrict__ conv_w, const float* __restrict__ conv_b,
                 u16* __restrict__ h_own, float* __restrict__ pool, int layer) {
    const int sb = blockIdx.x;
    const int tid = threadIdx.x;           // 640 = 5 rows * 128 cols
    const int r = 123 + tid / 128, c = tid & 127;
    __shared__ float gw[6][130];
    __shared__ float hw[2][5][130];
    __shared__ float wls[48], bls[4];
    if (tid < 48) wls[tid] = conv_w[layer * 48 + tid];
    if (tid < 4)  bls[tid] = conv_b[layer * 4 + tid];
    hw[0][tid / 128][(tid & 127) + 1] = 0.f;     // zero t=-1 state
    hw[1][tid / 128][(tid & 127) + 1] = 0.f;
    if (tid < 10) { hw[tid / 5][tid % 5][0] = 0.f; hw[tid / 5][tid % 5][129] = 0.f; }
    const size_t plane = (size_t)DD * DD;
    float c_reg = 0.f, pr = -1e30f;
    int cur = 0;
    for (int t = 0; t < LL; ++t) {
        __syncthreads();                       // prev-t window fully consumed
        for (int e = tid; e < 6 * 130; e += 640) {
            int rr = e / 130, cc2 = e % 130 - 1;
            float v = 0.f;
            if (t > 0 && cc2 >= 0 && cc2 < DD)
                v = bf2f(h_own[((size_t)(t - 1) * NSB + sb) * plane + (size_t)(117 + rr) * DD + cc2]);
            gw[rr][cc2 + 1] = v;
        }
        __syncthreads();
        float a0 = bls[0], a1 = bls[1], a2 = bls[2], a3 = bls[3];
        #pragma unroll
        for (int kh = 0; kh < 4; ++kh) {
            int hr = 2 * r - 129 + kh;         // 117..128
            #pragma unroll
            for (int kw = 0; kw < 3; ++kw) {
                float v;
                if (hr <= 122)      v = gw[hr - 117][c + kw];
                else if (hr <= 127) v = hw[cur][hr - 123][c + kw];
                else                v = 0.f;
                a0 += v * wls[0 * 12 + kh * 3 + kw];
                a1 += v * wls[1 * 12 + kh * 3 + kw];
                a2 += v * wls[2 * 12 + kh * 3 + kw];
                a3 += v * wls[3 * 12 + kh * 3 + kw];
            }
        }
        float fg = sigm(a0), ig = sigm(a1), og = sigm(a2), cs = tanh_fast(a3);
        c_reg = fg * c_reg + ig * cs;
        float hn = og * tanh_fast(c_reg);
        h_own[((size_t)t * NSB + sb) * plane + (size_t)r * DD + c] = f2bf(hn);
        hw[cur ^ 1][r - 123][c + 1] = hn;
        if (layer) pr = fmaxf(pr, hn);
        cur ^= 1;
    }
    if (layer) pool[(size_t)sb * plane + (size_t)r * DD + c] = pr;
}

// ---------------- final: linear + log_softmax ----------------
__global__ void final_kernel(const float* __restrict__ pool,
                             const float* __restrict__ lin_w,
                             const float* __restrict__ lin_b,
                             float* __restrict__ out) {
    const int b = blockIdx.x;
    const int tid = threadIdx.x;  // 256
    const int DD2 = DD * DD;
    const float* pq = pool + (size_t)b * DD2;
    const float* pa = pool + (size_t)(BB + b) * DD2;
    float s0 = 0.f, s1 = 0.f;
    for (int j = tid; j < DD2; j += 256) {
        float vq = pq[j], va = pa[j];
        s0 += vq * lin_w[j]           + va * lin_w[DD2 + j];
        s1 += vq * lin_w[2 * DD2 + j] + va * lin_w[3 * DD2 + j];
    }
    #pragma unroll
    for (int o = 32; o; o >>= 1) {
        s0 += __shfl_down(s0, o);
        s1 += __shfl_down(s1, o);
    }
    __shared__ float sh0[4], sh1[4];
    int wid = tid >> 6, lane = tid & 63;
    if (lane == 0) { sh0[wid] = s0; sh1[wid] = s1; }
    __syncthreads();
    if (tid == 0) {
        float a0 = sh0[0] + sh0[1] + sh0[2] + sh0[3] + lin_b[0];
        float a1 = sh1[0] + sh1[1] + sh1[2] + sh1[3] + lin_b[1];
        float m = fmaxf(a0, a1);
        float lse = m + logf(expf(a0 - m) + expf(a1 - m));
        out[b * 2 + 0] = a0 - lse;
        out[b * 2 + 1] = a1 - lse;
    }
}

extern "C" void kernel_launch(void* const* d_in, const int* in_sizes, int n_in,
                              void* d_out, int out_size, void* d_ws, size_t ws_size,
                              hipStream_t stream) {
    const int*   q      = (const int*)d_in[0];
    const int*   a      = (const int*)d_in[1];
    const float* embed  = (const float*)d_in[2];
    const float* conv_w = (const float*)d_in[3];
    const float* conv_b = (const float*)d_in[4];
    const float* lin_w  = (const float*)d_in[5];
    const float* lin_b  = (const float*)d_in[6];
    float* out = (float*)d_out;

    // ws: xe_all 1.3MB | inv | pool 4MB | h1 84MB | h2 84MB | gates 3x21MB  => ~236MB
    const size_t plane = (size_t)DD * DD;
    float* ws      = (float*)d_ws;
    float* xe_all  = ws;
    float* inv_all = xe_all + (size_t)NU * DD;
    float* pool    = inv_all + NU;
    u16*   h1      = (u16*)(pool + (size_t)NSB * plane);
    u16*   h2      = h1 + (size_t)LL * NSB * plane;
    float* g_fg    = (float*)(h2 + (size_t)LL * NSB * plane);
    float* g_ic    = g_fg + (size_t)LL * NSB * 16 * DD;
    float* g_og    = g_ic + (size_t)LL * NSB * 16 * DD;

    prep_kernel<<<(NU + 3) / 4, 256, 0, stream>>>(q, a, embed, xe_all, inv_all);

    // levels >=1 (each depends only on strictly lower rows at t-1):
    // {row0, nrows, R, log2nr}
    const int levs[5][4] = {{63,16,8,4},{79,16,8,4},{95,16,8,4},{111,8,8,3},{119,4,4,2}};

    for (int layer = 0; layer < 2; ++layer) {
        const u16* xt = layer ? h1 : nullptr;
        u16* hh       = layer ? h2 : h1;
        float* pl     = layer ? pool : nullptr;
        if (layer == 0)
            lev0_l1_kernel<<<dim3(32, NSB), dim3(128, 2), 0, stream>>>(
                xe_all, inv_all, conv_w, conv_b, h1);
        else
            lev0_l2_kernel<<<dim3(32, NSB), dim3(128, 2), 0, stream>>>(
                h1, conv_w, conv_b, h2, pool);
        for (int k = 0; k < 5; ++k) {
            int r0 = levs[k][0], nr = levs[k][1], R = levs[k][2], l2 = levs[k][3];
            gates_kernel<<<dim3(nr / R, NSB, LL), dim3(128, R), 0, stream>>>(
                xe_all, inv_all, conv_w, conv_b, xt, hh,
                g_fg, g_ic, g_og, layer, r0, nr, R);
            scan_kernel<<<(NSB * nr * DD) / 256, 256, 0, stream>>>(
                g_fg, g_ic, g_og, hh, pl, r0, nr, l2);
        }
        tail_kernel<<<NSB, 640, 0, stream>>>(conv_w, conv_b, hh, pl, layer);
    }

    final_kernel<<<BB, 256, 0, stream>>>(pool, lin_w, lin_b, out);
}